// Round 19
// baseline (123.999 us; speedup 1.0000x reference)
//
#include <hip/hip_runtime.h>

// Problem constants
#define NROWS 65536   // 64*64*32*32 / 64
#define KC    1024
#define DD    64

// Output layout (floats) in d_out
#define QOFF  0                     // quantized_st: 4194304
#define IOFF  4194304               // indices:        65536
#define WOFF  4259840               // new_weight:     65536
#define CSOFF 4325376               // cs:              1024
#define EAOFF 4326400               // new_embed_avg:  65536

// Workspace layout (float offsets)
#define WS_CODESQ  0        // 1056 f (1024 used)
#define WS_COUNTS  1056     // 1024 f
#define WS_RCCNT   2080     // 16 int
#define WS_CURSOR  2096     // 1024 int
#define WS_OFFS    3120     // 1024 int
#define WS_CSFIN   4144     // 1024 f
#define WS_DW      5168     // 65536 f
#define WS_WSWZ    70704    // 131072 halves = 65536 f (swizzled codebook tiles)
#define WS_IDX     137264   // 65536 int
#define WS_RCLIST  202800   // 65536 int
#define WS_ROWLIST 268336   // 65536 int
#define WS_PACKED  333872   // 65536 u64 = 131072 f (8B-aligned)

#define MARGIN 5e-5f
#define DECIDED_BIT 0x10000

typedef _Float16 half8 __attribute__((ext_vector_type(8)));
typedef float    floatx4 __attribute__((ext_vector_type(4)));

// POD 4-float vector usable through address_space(4) pointers.
struct F4 { float x, y, z, w; };
typedef const __attribute__((address_space(4))) F4    c4F4;
typedef const __attribute__((address_space(4))) float c4f;

__device__ __forceinline__ unsigned f2ord(float f) {
    unsigned u = __float_as_uint(f);
    return (u & 0x80000000u) ? ~u : (u | 0x80000000u);
}

// median(a,b,c) in one VALU op (no NaNs in our data).
__device__ __forceinline__ float med3f(float a, float b, float c) {
    float d;
    asm("v_med3_f32 %0, %1, %2, %3" : "=v"(d) : "v"(a), "v"(b), "v"(c));
    return d;
}

// Exact rowsq: numpy pairwise order over float4-held row (R5-R18 proven).
__device__ __forceinline__ float rowsq4(const float4* xv) {
    float4 re, ro;
    re.x = __fmul_rn(xv[0].x, xv[0].x); re.y = __fmul_rn(xv[0].y, xv[0].y);
    re.z = __fmul_rn(xv[0].z, xv[0].z); re.w = __fmul_rn(xv[0].w, xv[0].w);
    ro.x = __fmul_rn(xv[1].x, xv[1].x); ro.y = __fmul_rn(xv[1].y, xv[1].y);
    ro.z = __fmul_rn(xv[1].z, xv[1].z); ro.w = __fmul_rn(xv[1].w, xv[1].w);
#pragma unroll
    for (int i = 2; i < 16; i += 2) {
        re.x = __fadd_rn(re.x, __fmul_rn(xv[i].x, xv[i].x));
        re.y = __fadd_rn(re.y, __fmul_rn(xv[i].y, xv[i].y));
        re.z = __fadd_rn(re.z, __fmul_rn(xv[i].z, xv[i].z));
        re.w = __fadd_rn(re.w, __fmul_rn(xv[i].w, xv[i].w));
        ro.x = __fadd_rn(ro.x, __fmul_rn(xv[i + 1].x, xv[i + 1].x));
        ro.y = __fadd_rn(ro.y, __fmul_rn(xv[i + 1].y, xv[i + 1].y));
        ro.z = __fadd_rn(ro.z, __fmul_rn(xv[i + 1].z, xv[i + 1].z));
        ro.w = __fadd_rn(ro.w, __fmul_rn(xv[i + 1].w, xv[i + 1].w));
    }
    return __fadd_rn(__fadd_rn(__fadd_rn(re.x, re.y), __fadd_rn(re.z, re.w)),
                     __fadd_rn(__fadd_rn(ro.x, ro.y), __fadd_rn(ro.z, ro.w)));
}

// ---- Kernel A: exact code_sq + SWIZZLED split-f16 codebook + zero cnts ----
// Subtile s (16 codes, 2048 halves, contiguous at halves [s*2048, +2048)):
// [bh q=0..3 | bh q=4..7 | bl q=0..3 | bl q=4..7]; element (q,c,j) at
// q*128 + c*8 + j (hi) / +1024 (lo). Wave B-fragment reads are LINEAR 1KB.
__global__ void prep_kernel(const float* __restrict__ weight,
                            float* __restrict__ code_sq,
                            _Float16* __restrict__ wswz,
                            float* __restrict__ counts,
                            int* __restrict__ rccnt) {
    int c = blockIdx.x * blockDim.x + threadIdx.x;
    if (c >= KC) return;
    counts[c] = 0.0f;
    if (c == 0) rccnt[0] = 0;
    float4 wv4[16];
    const float4* pw = reinterpret_cast<const float4*>(weight + (size_t)c * DD);
#pragma unroll
    for (int i = 0; i < 16; ++i) wv4[i] = pw[i];
    code_sq[c] = rowsq4(wv4);
    float w64[64];
#pragma unroll
    for (int i = 0; i < 16; ++i) {
        w64[4 * i] = wv4[i].x; w64[4 * i + 1] = wv4[i].y;
        w64[4 * i + 2] = wv4[i].z; w64[4 * i + 3] = wv4[i].w;
    }
    const int t32 = c >> 5;
    const int s16 = (c >> 4) & 1;
    const int cl  = c & 15;
    const size_t base = (size_t)t32 * 4096 + s16 * 2048 + cl * 8;
#pragma unroll
    for (int q = 0; q < 8; ++q) {
        half8 h, l;
#pragma unroll
        for (int j = 0; j < 8; ++j) {
            float s = w64[q * 8 + j] * 1024.0f;    // exact (2^10)
            _Float16 hh = (_Float16)s;
            h[j] = hh;
            l[j] = (_Float16)(s - (float)hh);      // exact residual, rounded
        }
        *reinterpret_cast<half8*>(wswz + base + q * 128)        = h;
        *reinterpret_cast<half8*>(wswz + base + 1024 + q * 128) = l;
    }
}

// ---- Kernel B: compensated-f16 MFMA scan; WAVE-PRIVATE double-buffered
//      LDS subtiles + per-wave counted vmcnt -> NO barriers in main loop.
//      4 waves (M2 x K2), 1024 blocks -> 4 blocks/CU. ----
__global__ __launch_bounds__(256, 4) void vq_scan(
    const float* __restrict__ x_in, const float* __restrict__ weight,
    const float* __restrict__ code_sq, const _Float16* __restrict__ wswz,
    float* __restrict__ out, float* __restrict__ counts,
    int* __restrict__ idxbuf, int* __restrict__ rccnt, int* __restrict__ rclist,
    unsigned long long* __restrict__ packed) {

    __shared__ __align__(16) _Float16 lds_b[4][2][2048];  // wave-private 2x4KB
    __shared__ float lds_csq[KC];                         // 4KB
    __shared__ float sm1[4][32], sm2[4][32];
    __shared__ int   si1[4][32];
    __shared__ int   idx_l[64];

    const int tid  = threadIdx.x;
    const int lane = tid & 63;
    const int w    = tid >> 6;       // wave 0..3
    const int wm   = w & 1;          // M-split group
    const int wsel = w >> 1;         // K-split: subtile 0 or 1
    const int l15  = lane & 15;
    const int g    = lane >> 4;

    const int blockRow0 = blockIdx.x * 64;
    const int waveRow0  = blockRow0 + wm * 32;

    const char* gsrc0 = reinterpret_cast<const char*>(wswz);
    // Wave's i-th subtile = global subtile (2i + wsel) = bytes i*8192 + wsel*4096.
    const size_t wbase = (size_t)wsel * 4096;

    // DMA this wave's subtile i into private buffer b (1KB x 4 per wave).
#define DMA_SUBTILE(i_, b_) do {                                              \
        const char* s_ = gsrc0 + wbase + (size_t)(i_) * 8192;                 \
        char* d_ = (char*)lds_b[w][b_];                                       \
        _Pragma("unroll")                                                     \
        for (int j_ = 0; j_ < 4; ++j_) {                                      \
            __builtin_amdgcn_global_load_lds(                                 \
                (__attribute__((address_space(1))) void*)(s_ + lane * 16 + j_ * 1024), \
                (__attribute__((address_space(3))) void*)(d_ + lane * 16 + j_ * 1024), \
                16, 0, 0);                                                    \
        }                                                                     \
    } while (0)

    // Prologue: subtile 0 -> buf 0.
    DMA_SUBTILE(0, 0);

    // Stage csq to LDS (all threads).
#pragma unroll
    for (int i = 0; i < 4; ++i) lds_csq[tid + i * 256] = code_sq[tid + i * 256];

    // A fragments: 32 rows split into hi/lo f16. [tile(2)][khalf(2)]
    half8 ah[4], al[4];
#pragma unroll
    for (int t = 0; t < 2; ++t) {
#pragma unroll
        for (int kh = 0; kh < 2; ++kh) {
            const float4* p4 = reinterpret_cast<const float4*>(
                x_in + (size_t)(waveRow0 + t * 16 + l15) * DD + kh * 32 + g * 8);
            float4 v0 = p4[0], v1 = p4[1];
            float vals[8] = {v0.x, v0.y, v0.z, v0.w, v1.x, v1.y, v1.z, v1.w};
            half8 hh, ll;
#pragma unroll
            for (int j = 0; j < 8; ++j) {
                _Float16 h = (_Float16)vals[j];
                hh[j] = h;
                ll[j] = (_Float16)(vals[j] - (float)h);
            }
            ah[t * 2 + kh] = hh;
            al[t * 2 + kh] = ll;
        }
    }
    __syncthreads();   // csq visible to all waves (also covers prologue DMA)

    float m1[2][4], m2[2][4];
    int   i1[2][4];
#pragma unroll
    for (int t = 0; t < 2; ++t)
#pragma unroll
        for (int r = 0; r < 4; ++r) { m1[t][r] = INFINITY; m2[t][r] = INFINITY; i1[t][r] = 0; }

    // Per-wave compute on private buffer b for subtile index i.
#define COMPUTE_SUBTILE(i_, b_) do {                                          \
        const _Float16* S = lds_b[w][b_];                                     \
        half8 bh0 = *reinterpret_cast<const half8*>(S + g * 128 + l15 * 8);   \
        half8 bh1 = *reinterpret_cast<const half8*>(S + 512 + g * 128 + l15 * 8); \
        half8 bl0 = *reinterpret_cast<const half8*>(S + 1024 + g * 128 + l15 * 8); \
        half8 bl1 = *reinterpret_cast<const half8*>(S + 1536 + g * 128 + l15 * 8); \
        const int code = (i_) * 32 + wsel * 16 + l15;                         \
        const float csq = lds_csq[code];                                      \
        _Pragma("unroll")                                                     \
        for (int t = 0; t < 2; ++t) {                                         \
            floatx4 c1 = {0.f, 0.f, 0.f, 0.f};                                \
            floatx4 c2 = {0.f, 0.f, 0.f, 0.f};                                \
            c1 = __builtin_amdgcn_mfma_f32_16x16x32_f16(al[t * 2 + 0], bh0, c1, 0, 0, 0); \
            c2 = __builtin_amdgcn_mfma_f32_16x16x32_f16(al[t * 2 + 1], bh1, c2, 0, 0, 0); \
            c1 = __builtin_amdgcn_mfma_f32_16x16x32_f16(ah[t * 2 + 0], bl0, c1, 0, 0, 0); \
            c2 = __builtin_amdgcn_mfma_f32_16x16x32_f16(ah[t * 2 + 1], bl1, c2, 0, 0, 0); \
            c1 = __builtin_amdgcn_mfma_f32_16x16x32_f16(ah[t * 2 + 0], bh0, c1, 0, 0, 0); \
            c2 = __builtin_amdgcn_mfma_f32_16x16x32_f16(ah[t * 2 + 1], bh1, c2, 0, 0, 0); \
            _Pragma("unroll")                                                 \
            for (int r = 0; r < 4; ++r) {                                     \
                float s = fmaf(c1[r] + c2[r], -0x1p-9f, csq);                 \
                float mo = m1[t][r];                                          \
                m2[t][r] = med3f(s, mo, m2[t][r]);                            \
                i1[t][r] = (s < mo) ? code : i1[t][r];                        \
                m1[t][r] = fminf(mo, s);                                      \
            }                                                                 \
        }                                                                     \
    } while (0)

    // Main loop: 32 subtiles, depth-1 DMA pipeline, counted per-wave vmcnt.
    for (int i = 0; i < 31; ++i) {
        DMA_SUBTILE(i + 1, (i + 1) & 1);
        // Wait for subtile i's loads (the newest 4 are subtile i+1's).
        asm volatile("s_waitcnt vmcnt(4)" ::: "memory");
        __builtin_amdgcn_sched_barrier(0);
        COMPUTE_SUBTILE(i, i & 1);
    }
    asm volatile("s_waitcnt vmcnt(0)" ::: "memory");
    __builtin_amdgcn_sched_barrier(0);
    COMPUTE_SUBTILE(31, 1);

#undef DMA_SUBTILE
#undef COMPUTE_SUBTILE

    // Cross-lane argmin reduce within each 16-lane group (butterfly).
#pragma unroll
    for (int t = 0; t < 2; ++t)
#pragma unroll
        for (int r = 0; r < 4; ++r)
#pragma unroll
            for (int mk = 1; mk < 16; mk <<= 1) {
                float o1 = __shfl_xor(m1[t][r], mk);
                float o2 = __shfl_xor(m2[t][r], mk);
                int   oi = __shfl_xor(i1[t][r], mk);
                float n2 = fminf(fminf(m2[t][r], o2), fmaxf(m1[t][r], o1));
                bool sel = (o1 < m1[t][r]) || (o1 == m1[t][r] && oi < i1[t][r]);
                m1[t][r] = sel ? o1 : m1[t][r];
                i1[t][r] = sel ? oi : i1[t][r];
                m2[t][r] = n2;
            }

    // Publish per-wave partials (8 rows per l15==0 lane; rib in [0,32)).
    if (l15 == 0) {
#pragma unroll
        for (int t = 0; t < 2; ++t)
#pragma unroll
            for (int r = 0; r < 4; ++r) {
                int rib = t * 16 + g * 4 + r;
                sm1[w][rib] = m1[t][r];
                sm2[w][rib] = m2[t][r];
                si1[w][rib] = i1[t][r];
            }
    }
    __syncthreads();

    // Merge wave pairs (wm, wm+2): threads 0..63 each own one block row.
    if (tid < 64) {
        int pwm = tid >> 5;
        int rib = tid & 31;
        float bm1 = sm1[pwm][rib], bm2 = sm2[pwm][rib];
        int bi = si1[pwm][rib];
        {
            float v1 = sm1[pwm + 2][rib];
            float v2 = sm2[pwm + 2][rib];
            int   vi = si1[pwm + 2][rib];
            if (v1 < bm1 || (v1 == bm1 && vi < bi)) {
                bm2 = fminf(bm1, v2);
                bm1 = v1; bi = vi;
            } else {
                bm2 = fminf(bm2, v1);
            }
        }
        int grow = blockRow0 + tid;   // pwm*32 + rib == tid
        if (bm2 - bm1 >= MARGIN) {
            idxbuf[grow] = bi | DECIDED_BIT;
            out[IOFF + grow] = (float)bi;
            atomicAdd(&counts[bi], 1.0f);
            idx_l[tid] = bi;
        } else {
            packed[grow] = 0xFFFFFFFFFFFFFFFFull;   // re-init (covers stale)
            int pos = atomicAdd(rccnt, 1);
            rclist[pos] = grow;
            idx_l[tid] = -1;
        }
    }
    __syncthreads();

    // Fused epilogue: quantized for DECIDED rows (64 rows x 16 f4 = 1024 f4).
    {
        const float4* xin4 = reinterpret_cast<const float4*>(x_in);
        const float4* w4g  = reinterpret_cast<const float4*>(weight);
        float4* q4 = reinterpret_cast<float4*>(out + QOFF);
        const size_t blk4 = (size_t)blockRow0 * 16;
#pragma unroll
        for (int j = 0; j < 4; ++j) {
            int f4i = tid + j * 256;
            int rl  = f4i >> 4;
            int d4  = f4i & 15;
            int idx = idx_l[rl];
            if (idx < 0) continue;
            float4 xq = xin4[blk4 + f4i];
            float4 wq = w4g[idx * 16 + d4];
            float4 qv;
            qv.x = __fadd_rn(xq.x, __fsub_rn(wq.x, xq.x));
            qv.y = __fadd_rn(xq.y, __fsub_rn(wq.y, xq.y));
            qv.z = __fadd_rn(xq.z, __fsub_rn(wq.z, xq.z));
            qv.w = __fadd_rn(xq.w, __fsub_rn(wq.w, xq.w));
            q4[blk4 + f4i] = qv;
        }
    }
}

// ---- Kernel C: exact recheck, parallel over (64-row chunk) x (64-code chunk) ----
__global__ __launch_bounds__(256, 4) void vq_recheck(
    const float* __restrict__ x_in, const float* __restrict__ weight,
    const float* __restrict__ code_sq,
    unsigned long long* __restrict__ packed,
    const int* __restrict__ rccnt, const int* __restrict__ rclist) {

    const int nrc = rccnt[0];
    const int nitems = ((nrc + 63) >> 6) * 16;

    const int tid  = threadIdx.x;
    const int lane = tid & 63;
    const int wvu  = __builtin_amdgcn_readfirstlane(tid >> 6);

    for (int item = blockIdx.x; item < nitems; item += gridDim.x) {
        const int rb     = (item >> 4) * 64;
        const int cchunk = item & 15;
        const bool valid = (rb + lane) < nrc;
        const int  grow  = rclist[valid ? rb + lane : rb];

        float4 xv[16];
        const float4* px = reinterpret_cast<const float4*>(x_in + (size_t)grow * DD);
#pragma unroll
        for (int i = 0; i < 16; ++i) xv[i] = px[i];
        const float rs = rowsq4(xv);

        const int k0 = cchunk * 64 + wvu * 16;    // wave-uniform
        unsigned long long wa = (unsigned long long)(weight + (size_t)k0 * DD);
        unsigned long long ca = (unsigned long long)(code_sq + k0);
        unsigned wal = __builtin_amdgcn_readfirstlane((unsigned)wa);
        unsigned wah = __builtin_amdgcn_readfirstlane((unsigned)(wa >> 32));
        unsigned cal = __builtin_amdgcn_readfirstlane((unsigned)ca);
        unsigned cah = __builtin_amdgcn_readfirstlane((unsigned)(ca >> 32));
        c4F4* wb4 = (c4F4*)(((unsigned long long)wah << 32) | wal);
        c4f*  cb  = (c4f*)(((unsigned long long)cah << 32) | cal);

        float best = INFINITY;
        int bidx = 0x7fffffff;

#pragma unroll 2
        for (int k = 0; k < 16; ++k) {
            float a0 = 0.f, a1 = 0.f, a2 = 0.f, a3 = 0.f;
#pragma unroll
            for (int i = 0; i < 16; ++i) {
                F4 w4;
                w4.x = wb4[k * 16 + i].x;
                w4.y = wb4[k * 16 + i].y;
                w4.z = wb4[k * 16 + i].z;
                w4.w = wb4[k * 16 + i].w;
                a0 += xv[i].x * w4.x;
                a1 += xv[i].y * w4.y;
                a2 += xv[i].z * w4.z;
                a3 += xv[i].w * w4.w;
            }
            float dot = (a0 + a1) + (a2 + a3);
            float csq = cb[k];
            float dst = __fsub_rn(__fadd_rn(rs, csq), __fmul_rn(2.0f, dot));
            int kg = k0 + k;
            if (dst < best) { best = dst; bidx = kg; }
        }

        if (valid) {
            unsigned long long p =
                ((unsigned long long)f2ord(best) << 32) | (unsigned)bidx;
            atomicMin(&packed[grow], p);
        }
    }
}

// ---- Kernel D: fused rc_finalize + exclusive-scan (offs) + cs; 1 block ----
__global__ void rc_offsets_cs(const unsigned long long* __restrict__ packed,
                              const int* __restrict__ rccnt,
                              const int* __restrict__ rclist,
                              const float* __restrict__ cluster_size,
                              float* __restrict__ out, int* __restrict__ idxbuf,
                              float* __restrict__ counts,
                              int* __restrict__ offs, int* __restrict__ cursor,
                              float* __restrict__ cs_fin) {
    __shared__ int   hist[1024];
    __shared__ int   sc[1024];
    __shared__ float sb[1024];
    int k = threadIdx.x;
    hist[k] = 0;
    __syncthreads();
    const int nrc = rccnt[0];
    for (int i = k; i < nrc; i += 1024) {
        int grow = rclist[i];
        int bidx = (int)(packed[grow] & 0xFFFFFFFFull);
        out[IOFF + grow] = (float)bidx;
        idxbuf[grow] = bidx;                     // no DECIDED bit -> flagged
        atomicAdd(&hist[bidx], 1);
    }
    __syncthreads();
    int c = (int)counts[k] + hist[k];
    counts[k] = (float)c;                        // final counts for dw_q
    float ce = 0.99f * cluster_size[k] + 0.01f * (float)c;
    sc[k] = c;
    sb[k] = ce;
    __syncthreads();
    for (int off = 1; off < 1024; off <<= 1) {
        int v = (k >= off) ? sc[k - off] : 0;
        __syncthreads();
        sc[k] += v;
        __syncthreads();
    }
    offs[k] = sc[k] - c;
    cursor[k] = 0;
    for (int off = 512; off > 0; off >>= 1) {
        if (k < off) sb[k] += sb[k + off];
        __syncthreads();
    }
    float n = sb[0];
    float v = ((ce + 1e-5f) / (n + 0.01024f)) * n;
    out[CSOFF + k] = v;
    cs_fin[k] = v;
}

// ---- Kernel E: scatter rows into per-code buckets (flag -> bit 31) ----
__global__ void scatter_kernel(const int* __restrict__ idxbuf,
                               const int* __restrict__ offs,
                               int* __restrict__ cursor,
                               int* __restrict__ rowlist) {
    int r = blockIdx.x * blockDim.x + threadIdx.x;
    if (r >= NROWS) return;
    int v = idxbuf[r];
    int k = v & 1023;
    int pos = atomicAdd(&cursor[k], 1);
    rowlist[offs[k] + pos] = r | ((v & DECIDED_BIT) ? 0 : 0x80000000);
}

// ---- Kernel F: per-code dw reduction + fused EMA/new-weight; quantized
//      stores only for FLAGGED rows (bit 31 of rowlist entry). ----
__global__ __launch_bounds__(512) void dw_q_kernel(
    const float* __restrict__ x_in,
    const float* __restrict__ weight,
    const float* __restrict__ counts,
    const int* __restrict__ offs,
    const int* __restrict__ rowlist,
    const float* __restrict__ embed_avg,
    const float* __restrict__ cs_fin,
    float* __restrict__ out, float* __restrict__ dw) {
    __shared__ float wsh[64];
    __shared__ float part[8][64];

    const int k    = blockIdx.x;
    const int tid  = threadIdx.x;
    const int lane = tid & 63;
    const int wv   = tid >> 6;      // 0..7

    if (tid < 64) wsh[tid] = weight[(size_t)k * DD + tid];
    __syncthreads();

    const int cnt  = (int)counts[k];
    const int base = offs[k];
    const float wk = wsh[lane];

    float acc = 0.f;
    int i = wv;
    // 4 rows in flight per wave (stride 8 per wave, 8 waves).
    for (; i + 24 < cnt; i += 32) {
        int e0 = rowlist[base + i];
        int e1 = rowlist[base + i + 8];
        int e2 = rowlist[base + i + 16];
        int e3 = rowlist[base + i + 24];
        int r0 = e0 & 0x7fffffff;
        int r1 = e1 & 0x7fffffff;
        int r2 = e2 & 0x7fffffff;
        int r3 = e3 & 0x7fffffff;
        float x0 = x_in[(size_t)r0 * DD + lane];
        float x1 = x_in[(size_t)r1 * DD + lane];
        float x2 = x_in[(size_t)r2 * DD + lane];
        float x3 = x_in[(size_t)r3 * DD + lane];
        if (e0 < 0) out[QOFF + (size_t)r0 * DD + lane] = __fadd_rn(x0, __fsub_rn(wk, x0));
        if (e1 < 0) out[QOFF + (size_t)r1 * DD + lane] = __fadd_rn(x1, __fsub_rn(wk, x1));
        if (e2 < 0) out[QOFF + (size_t)r2 * DD + lane] = __fadd_rn(x2, __fsub_rn(wk, x2));
        if (e3 < 0) out[QOFF + (size_t)r3 * DD + lane] = __fadd_rn(x3, __fsub_rn(wk, x3));
        acc = __fadd_rn(acc, x0);
        acc = __fadd_rn(acc, x1);
        acc = __fadd_rn(acc, x2);
        acc = __fadd_rn(acc, x3);
    }
    for (; i < cnt; i += 8) {
        int e = rowlist[base + i];
        int r = e & 0x7fffffff;
        float xq = x_in[(size_t)r * DD + lane];
        if (e < 0) out[QOFF + (size_t)r * DD + lane] = __fadd_rn(xq, __fsub_rn(wk, xq));
        acc = __fadd_rn(acc, xq);
    }
    part[wv][lane] = acc;
    __syncthreads();
    if (tid < 64) {
        float s01 = __fadd_rn(part[0][tid], part[1][tid]);
        float s23 = __fadd_rn(part[2][tid], part[3][tid]);
        float s45 = __fadd_rn(part[4][tid], part[5][tid]);
        float s67 = __fadd_rn(part[6][tid], part[7][tid]);
        float s = __fadd_rn(__fadd_rn(s01, s23), __fadd_rn(s45, s67));
        int e = k * DD + tid;
        dw[e] = s;
        float na = 0.99f * embed_avg[e] + 0.01f * s;
        out[EAOFF + e] = na;
        out[WOFF + e] = na / cs_fin[k];
    }
}

extern "C" void kernel_launch(void* const* d_in, const int* in_sizes, int n_in,
                              void* d_out, int out_size, void* d_ws, size_t ws_size,
                              hipStream_t stream) {
    (void)in_sizes; (void)n_in; (void)out_size; (void)ws_size;
    const float* x       = (const float*)d_in[0];
    const float* weight  = (const float*)d_in[1];
    const float* cluster = (const float*)d_in[2];
    const float* eavg    = (const float*)d_in[3];
    float* out = (float*)d_out;
    float* wsf = (float*)d_ws;

    float*    code_sq = wsf + WS_CODESQ;
    float*    counts  = wsf + WS_COUNTS;
    int*      rccnt   = (int*)(wsf + WS_RCCNT);
    int*      cursor  = (int*)(wsf + WS_CURSOR);
    int*      offs    = (int*)(wsf + WS_OFFS);
    float*    cs_fin  = wsf + WS_CSFIN;
    float*    dwbuf   = wsf + WS_DW;
    _Float16* wswz    = (_Float16*)(wsf + WS_WSWZ);
    int*      idxbuf  = (int*)(wsf + WS_IDX);
    int*      rclist  = (int*)(wsf + WS_RCLIST);
    int*      rowlist = (int*)(wsf + WS_ROWLIST);
    unsigned long long* packed = (unsigned long long*)(wsf + WS_PACKED);

    hipLaunchKernelGGL(prep_kernel, dim3(16), dim3(64), 0, stream,
                       weight, code_sq, wswz, counts, rccnt);
    hipLaunchKernelGGL(vq_scan, dim3(1024), dim3(256), 0, stream,
                       x, weight, code_sq, wswz, out, counts, idxbuf, rccnt,
                       rclist, packed);
    hipLaunchKernelGGL(vq_recheck, dim3(2048), dim3(256), 0, stream,
                       x, weight, code_sq, packed, rccnt, rclist);
    hipLaunchKernelGGL(rc_offsets_cs, dim3(1), dim3(1024), 0, stream,
                       packed, rccnt, rclist, cluster, out, idxbuf, counts,
                       offs, cursor, cs_fin);
    hipLaunchKernelGGL(scatter_kernel, dim3(256), dim3(256), 0, stream,
                       idxbuf, offs, cursor, rowlist);
    hipLaunchKernelGGL(dw_q_kernel, dim3(1024), dim3(512), 0, stream,
                       x, weight, counts, offs, rowlist, eavg, cs_fin, out, dwbuf);
}

// Round 20
// 115.391 us; speedup vs baseline: 1.0746x; 1.0746x over previous
//
#include <hip/hip_runtime.h>

// Problem constants
#define NROWS 65536   // 64*64*32*32 / 64
#define KC    1024
#define DD    64

// Output layout (floats) in d_out
#define QOFF  0                     // quantized_st: 4194304
#define IOFF  4194304               // indices:        65536
#define WOFF  4259840               // new_weight:     65536
#define CSOFF 4325376               // cs:              1024
#define EAOFF 4326400               // new_embed_avg:  65536

// Workspace layout (float offsets)
#define WS_CODESQ  0        // 1056 f (1024 used)
#define WS_COUNTS  1056     // 1024 f
#define WS_RCCNT   2080     // 16 int
#define WS_CURSOR  2096     // 1024 int
#define WS_OFFS    3120     // 1024 int
#define WS_CSFIN   4144     // 1024 f
#define WS_DW      5168     // 65536 f
#define WS_WSWZ    70704    // 131072 halves = 65536 f (swizzled codebook tiles)
#define WS_IDX     137264   // 65536 int
#define WS_RCLIST  202800   // 65536 int
#define WS_ROWLIST 268336   // 65536 int
#define WS_PACKED  333872   // 65536 u64 = 131072 f (8B-aligned)

#define MARGIN 5e-5f
#define DECIDED_BIT 0x10000

typedef _Float16 half8 __attribute__((ext_vector_type(8)));
typedef float    floatx4 __attribute__((ext_vector_type(4)));

// POD 4-float vector usable through address_space(4) pointers.
struct F4 { float x, y, z, w; };
typedef const __attribute__((address_space(4))) F4    c4F4;
typedef const __attribute__((address_space(4))) float c4f;

__device__ __forceinline__ unsigned f2ord(float f) {
    unsigned u = __float_as_uint(f);
    return (u & 0x80000000u) ? ~u : (u | 0x80000000u);
}

// median(a,b,c) in one VALU op (no NaNs in our data).
__device__ __forceinline__ float med3f(float a, float b, float c) {
    float d;
    asm("v_med3_f32 %0, %1, %2, %3" : "=v"(d) : "v"(a), "v"(b), "v"(c));
    return d;
}

// Exact rowsq: numpy pairwise order over float4-held row (R5-R18 proven).
__device__ __forceinline__ float rowsq4(const float4* xv) {
    float4 re, ro;
    re.x = __fmul_rn(xv[0].x, xv[0].x); re.y = __fmul_rn(xv[0].y, xv[0].y);
    re.z = __fmul_rn(xv[0].z, xv[0].z); re.w = __fmul_rn(xv[0].w, xv[0].w);
    ro.x = __fmul_rn(xv[1].x, xv[1].x); ro.y = __fmul_rn(xv[1].y, xv[1].y);
    ro.z = __fmul_rn(xv[1].z, xv[1].z); ro.w = __fmul_rn(xv[1].w, xv[1].w);
#pragma unroll
    for (int i = 2; i < 16; i += 2) {
        re.x = __fadd_rn(re.x, __fmul_rn(xv[i].x, xv[i].x));
        re.y = __fadd_rn(re.y, __fmul_rn(xv[i].y, xv[i].y));
        re.z = __fadd_rn(re.z, __fmul_rn(xv[i].z, xv[i].z));
        re.w = __fadd_rn(re.w, __fmul_rn(xv[i].w, xv[i].w));
        ro.x = __fadd_rn(ro.x, __fmul_rn(xv[i + 1].x, xv[i + 1].x));
        ro.y = __fadd_rn(ro.y, __fmul_rn(xv[i + 1].y, xv[i + 1].y));
        ro.z = __fadd_rn(ro.z, __fmul_rn(xv[i + 1].z, xv[i + 1].z));
        ro.w = __fadd_rn(ro.w, __fmul_rn(xv[i + 1].w, xv[i + 1].w));
    }
    return __fadd_rn(__fadd_rn(__fadd_rn(re.x, re.y), __fadd_rn(re.z, re.w)),
                     __fadd_rn(__fadd_rn(ro.x, ro.y), __fadd_rn(ro.z, ro.w)));
}

// ---- Kernel A: exact code_sq + SWIZZLED split-f16 codebook + zero cnts ----
__global__ void prep_kernel(const float* __restrict__ weight,
                            float* __restrict__ code_sq,
                            _Float16* __restrict__ wswz,
                            float* __restrict__ counts,
                            int* __restrict__ rccnt) {
    int c = blockIdx.x * blockDim.x + threadIdx.x;
    if (c >= KC) return;
    counts[c] = 0.0f;
    if (c == 0) rccnt[0] = 0;
    float4 wv4[16];
    const float4* pw = reinterpret_cast<const float4*>(weight + (size_t)c * DD);
#pragma unroll
    for (int i = 0; i < 16; ++i) wv4[i] = pw[i];
    code_sq[c] = rowsq4(wv4);
    float w64[64];
#pragma unroll
    for (int i = 0; i < 16; ++i) {
        w64[4 * i] = wv4[i].x; w64[4 * i + 1] = wv4[i].y;
        w64[4 * i + 2] = wv4[i].z; w64[4 * i + 3] = wv4[i].w;
    }
    const int t32 = c >> 5;
    const int s16 = (c >> 4) & 1;
    const int cl  = c & 15;
    const size_t base = (size_t)t32 * 4096 + s16 * 2048 + cl * 8;
#pragma unroll
    for (int q = 0; q < 8; ++q) {
        half8 h, l;
#pragma unroll
        for (int j = 0; j < 8; ++j) {
            float s = w64[q * 8 + j] * 1024.0f;    // exact (2^10)
            _Float16 hh = (_Float16)s;
            h[j] = hh;
            l[j] = (_Float16)(s - (float)hh);      // exact residual, rounded
        }
        *reinterpret_cast<half8*>(wswz + base + q * 128)        = h;
        *reinterpret_cast<half8*>(wswz + base + 1024 + q * 128) = l;
    }
}

// ---- Kernel B: compensated-f16 MFMA scan; DMA staging, 16 barriers,
//      4 waves (M2 x K2), 1024 blocks. Fused quantized-write epilogue
//      for decided rows (flag bit 16 in idxbuf). [R18 proven best] ----
__global__ __launch_bounds__(256, 4) void vq_scan(
    const float* __restrict__ x_in, const float* __restrict__ weight,
    const float* __restrict__ code_sq, const _Float16* __restrict__ wswz,
    float* __restrict__ out, float* __restrict__ counts,
    int* __restrict__ idxbuf, int* __restrict__ rccnt, int* __restrict__ rclist,
    unsigned long long* __restrict__ packed) {

    __shared__ __align__(16) _Float16 lds_b[2][8192];  // 2 x 16KB (2-tile pair)
    __shared__ float lds_csq[KC];                      // 4KB
    __shared__ float sm1[4][32], sm2[4][32];
    __shared__ int   si1[4][32];
    __shared__ int   idx_l[64];

    const int tid  = threadIdx.x;
    const int lane = tid & 63;
    const int w    = tid >> 6;       // wave 0..3
    const int wm   = w & 1;          // M-split group
    const int wsel = w >> 1;         // K-split: subtile 0 or 1
    const int l15  = lane & 15;
    const int g    = lane >> 4;

    const int blockRow0 = blockIdx.x * 64;
    const int waveRow0  = blockRow0 + wm * 32;

    char* gsrc0 = const_cast<char*>(reinterpret_cast<const char*>(wswz));

    // Prologue: DMA tile-pair 0 into buf 0 (16KB; 4 x 16B per thread).
#pragma unroll
    for (int j = 0; j < 4; ++j) {
        __builtin_amdgcn_global_load_lds(
            (__attribute__((address_space(1))) void*)(gsrc0 + tid * 16 + j * 4096),
            (__attribute__((address_space(3))) void*)((char*)lds_b[0] + tid * 16 + j * 4096),
            16, 0, 0);
    }

    // Stage csq to LDS.
#pragma unroll
    for (int i = 0; i < 4; ++i) lds_csq[tid + i * 256] = code_sq[tid + i * 256];

    // A fragments: 32 rows split into hi/lo f16. [tile(2)][khalf(2)]
    half8 ah[4], al[4];
#pragma unroll
    for (int t = 0; t < 2; ++t) {
#pragma unroll
        for (int kh = 0; kh < 2; ++kh) {
            const float4* p4 = reinterpret_cast<const float4*>(
                x_in + (size_t)(waveRow0 + t * 16 + l15) * DD + kh * 32 + g * 8);
            float4 v0 = p4[0], v1 = p4[1];
            float vals[8] = {v0.x, v0.y, v0.z, v0.w, v1.x, v1.y, v1.z, v1.w};
            half8 hh, ll;
#pragma unroll
            for (int j = 0; j < 8; ++j) {
                _Float16 h = (_Float16)vals[j];
                hh[j] = h;
                ll[j] = (_Float16)(vals[j] - (float)h);
            }
            ah[t * 2 + kh] = hh;
            al[t * 2 + kh] = ll;
        }
    }
    __syncthreads();   // prologue DMA + csq staged

    float m1[2][4], m2[2][4];
    int   i1[2][4];
#pragma unroll
    for (int t = 0; t < 2; ++t)
#pragma unroll
        for (int r = 0; r < 4; ++r) { m1[t][r] = INFINITY; m2[t][r] = INFINITY; i1[t][r] = 0; }

    int cur = 0;
    for (int p = 0; p < 16; ++p) {
        // DMA next 64-code pair into the other buffer (hides under compute).
        if (p < 15) {
            char* src = gsrc0 + (size_t)(p + 1) * 16384;
            char* dst = (char*)lds_b[cur ^ 1];
#pragma unroll
            for (int j = 0; j < 4; ++j) {
                __builtin_amdgcn_global_load_lds(
                    (__attribute__((address_space(1))) void*)(src + tid * 16 + j * 4096),
                    (__attribute__((address_space(3))) void*)(dst + tid * 16 + j * 4096),
                    16, 0, 0);
            }
        }

        // Compute both 32-code tiles of buf[cur] (this wave's 16-code subtiles).
#pragma unroll
        for (int half = 0; half < 2; ++half) {
            const _Float16* S = lds_b[cur] + half * 4096 + wsel * 2048;
            half8 bh0 = *reinterpret_cast<const half8*>(S + g * 128 + l15 * 8);
            half8 bh1 = *reinterpret_cast<const half8*>(S + 512 + g * 128 + l15 * 8);
            half8 bl0 = *reinterpret_cast<const half8*>(S + 1024 + g * 128 + l15 * 8);
            half8 bl1 = *reinterpret_cast<const half8*>(S + 1536 + g * 128 + l15 * 8);
            const int code = p * 64 + half * 32 + wsel * 16 + l15;
            const float csq = lds_csq[code];
#pragma unroll
            for (int t = 0; t < 2; ++t) {
                // Chain-split: two independent 3-deep chains.
                floatx4 c1 = {0.f, 0.f, 0.f, 0.f};
                floatx4 c2 = {0.f, 0.f, 0.f, 0.f};
                c1 = __builtin_amdgcn_mfma_f32_16x16x32_f16(al[t * 2 + 0], bh0, c1, 0, 0, 0);
                c2 = __builtin_amdgcn_mfma_f32_16x16x32_f16(al[t * 2 + 1], bh1, c2, 0, 0, 0);
                c1 = __builtin_amdgcn_mfma_f32_16x16x32_f16(ah[t * 2 + 0], bl0, c1, 0, 0, 0);
                c2 = __builtin_amdgcn_mfma_f32_16x16x32_f16(ah[t * 2 + 1], bl1, c2, 0, 0, 0);
                c1 = __builtin_amdgcn_mfma_f32_16x16x32_f16(ah[t * 2 + 0], bh0, c1, 0, 0, 0);
                c2 = __builtin_amdgcn_mfma_f32_16x16x32_f16(ah[t * 2 + 1], bh1, c2, 0, 0, 0);
#pragma unroll
                for (int r = 0; r < 4; ++r) {
                    float s = fmaf(c1[r] + c2[r], -0x1p-9f, csq);  // csq - 2*dot
                    float mo = m1[t][r];
                    m2[t][r] = med3f(s, mo, m2[t][r]);   // median = new m2
                    i1[t][r] = (s < mo) ? code : i1[t][r];
                    m1[t][r] = fminf(mo, s);
                }
            }
        }

        __syncthreads();   // DMA drained (vmcnt) + all reads of buf[cur] done
        cur ^= 1;
    }

    // Cross-lane argmin reduce within each 16-lane group (butterfly).
#pragma unroll
    for (int t = 0; t < 2; ++t)
#pragma unroll
        for (int r = 0; r < 4; ++r)
#pragma unroll
            for (int mk = 1; mk < 16; mk <<= 1) {
                float o1 = __shfl_xor(m1[t][r], mk);
                float o2 = __shfl_xor(m2[t][r], mk);
                int   oi = __shfl_xor(i1[t][r], mk);
                float n2 = fminf(fminf(m2[t][r], o2), fmaxf(m1[t][r], o1));
                bool sel = (o1 < m1[t][r]) || (o1 == m1[t][r] && oi < i1[t][r]);
                m1[t][r] = sel ? o1 : m1[t][r];
                i1[t][r] = sel ? oi : i1[t][r];
                m2[t][r] = n2;
            }

    // Publish per-wave partials (8 rows per l15==0 lane; rib in [0,32)).
    if (l15 == 0) {
#pragma unroll
        for (int t = 0; t < 2; ++t)
#pragma unroll
            for (int r = 0; r < 4; ++r) {
                int rib = t * 16 + g * 4 + r;
                sm1[w][rib] = m1[t][r];
                sm2[w][rib] = m2[t][r];
                si1[w][rib] = i1[t][r];
            }
    }
    __syncthreads();

    // Merge wave pairs (wm, wm+2): threads 0..63 each own one block row.
    if (tid < 64) {
        int pwm = tid >> 5;
        int rib = tid & 31;
        float bm1 = sm1[pwm][rib], bm2 = sm2[pwm][rib];
        int bi = si1[pwm][rib];
        {
            float v1 = sm1[pwm + 2][rib];
            float v2 = sm2[pwm + 2][rib];
            int   vi = si1[pwm + 2][rib];
            if (v1 < bm1 || (v1 == bm1 && vi < bi)) {
                bm2 = fminf(bm1, v2);
                bm1 = v1; bi = vi;
            } else {
                bm2 = fminf(bm2, v1);
            }
        }
        int grow = blockRow0 + tid;   // pwm*32 + rib == tid
        if (bm2 - bm1 >= MARGIN) {
            idxbuf[grow] = bi | DECIDED_BIT;
            out[IOFF + grow] = (float)bi;
            atomicAdd(&counts[bi], 1.0f);
            idx_l[tid] = bi;
        } else {
            packed[grow] = 0xFFFFFFFFFFFFFFFFull;   // re-init (covers stale)
            int pos = atomicAdd(rccnt, 1);
            rclist[pos] = grow;
            idx_l[tid] = -1;
        }
    }
    __syncthreads();

    // Fused epilogue: quantized for DECIDED rows (64 rows x 16 f4 = 1024 f4).
    {
        const float4* xin4 = reinterpret_cast<const float4*>(x_in);
        const float4* w4g  = reinterpret_cast<const float4*>(weight);
        float4* q4 = reinterpret_cast<float4*>(out + QOFF);
        const size_t blk4 = (size_t)blockRow0 * 16;
#pragma unroll
        for (int j = 0; j < 4; ++j) {
            int f4i = tid + j * 256;
            int rl  = f4i >> 4;
            int d4  = f4i & 15;
            int idx = idx_l[rl];
            if (idx < 0) continue;
            float4 xq = xin4[blk4 + f4i];
            float4 wq = w4g[idx * 16 + d4];
            float4 qv;
            qv.x = __fadd_rn(xq.x, __fsub_rn(wq.x, xq.x));
            qv.y = __fadd_rn(xq.y, __fsub_rn(wq.y, xq.y));
            qv.z = __fadd_rn(xq.z, __fsub_rn(wq.z, xq.z));
            qv.w = __fadd_rn(xq.w, __fsub_rn(wq.w, xq.w));
            q4[blk4 + f4i] = qv;
        }
    }
}

// ---- Kernel C: exact recheck, parallel over (64-row chunk) x (64-code chunk) ----
__global__ __launch_bounds__(256, 4) void vq_recheck(
    const float* __restrict__ x_in, const float* __restrict__ weight,
    const float* __restrict__ code_sq,
    unsigned long long* __restrict__ packed,
    const int* __restrict__ rccnt, const int* __restrict__ rclist) {

    const int nrc = rccnt[0];
    const int nitems = ((nrc + 63) >> 6) * 16;

    const int tid  = threadIdx.x;
    const int lane = tid & 63;
    const int wvu  = __builtin_amdgcn_readfirstlane(tid >> 6);

    for (int item = blockIdx.x; item < nitems; item += gridDim.x) {
        const int rb     = (item >> 4) * 64;
        const int cchunk = item & 15;
        const bool valid = (rb + lane) < nrc;
        const int  grow  = rclist[valid ? rb + lane : rb];

        float4 xv[16];
        const float4* px = reinterpret_cast<const float4*>(x_in + (size_t)grow * DD);
#pragma unroll
        for (int i = 0; i < 16; ++i) xv[i] = px[i];
        const float rs = rowsq4(xv);

        const int k0 = cchunk * 64 + wvu * 16;    // wave-uniform
        unsigned long long wa = (unsigned long long)(weight + (size_t)k0 * DD);
        unsigned long long ca = (unsigned long long)(code_sq + k0);
        unsigned wal = __builtin_amdgcn_readfirstlane((unsigned)wa);
        unsigned wah = __builtin_amdgcn_readfirstlane((unsigned)(wa >> 32));
        unsigned cal = __builtin_amdgcn_readfirstlane((unsigned)ca);
        unsigned cah = __builtin_amdgcn_readfirstlane((unsigned)(ca >> 32));
        c4F4* wb4 = (c4F4*)(((unsigned long long)wah << 32) | wal);
        c4f*  cb  = (c4f*)(((unsigned long long)cah << 32) | cal);

        float best = INFINITY;
        int bidx = 0x7fffffff;

#pragma unroll 2
        for (int k = 0; k < 16; ++k) {
            float a0 = 0.f, a1 = 0.f, a2 = 0.f, a3 = 0.f;
#pragma unroll
            for (int i = 0; i < 16; ++i) {
                F4 w4;
                w4.x = wb4[k * 16 + i].x;
                w4.y = wb4[k * 16 + i].y;
                w4.z = wb4[k * 16 + i].z;
                w4.w = wb4[k * 16 + i].w;
                a0 += xv[i].x * w4.x;
                a1 += xv[i].y * w4.y;
                a2 += xv[i].z * w4.z;
                a3 += xv[i].w * w4.w;
            }
            float dot = (a0 + a1) + (a2 + a3);
            float csq = cb[k];
            float dst = __fsub_rn(__fadd_rn(rs, csq), __fmul_rn(2.0f, dot));
            int kg = k0 + k;
            if (dst < best) { best = dst; bidx = kg; }
        }

        if (valid) {
            unsigned long long p =
                ((unsigned long long)f2ord(best) << 32) | (unsigned)bidx;
            atomicMin(&packed[grow], p);
        }
    }
}

// ---- Kernel D: fused rc_finalize + exclusive-scan (offs) + cs; 1 block ----
__global__ void rc_offsets_cs(const unsigned long long* __restrict__ packed,
                              const int* __restrict__ rccnt,
                              const int* __restrict__ rclist,
                              const float* __restrict__ cluster_size,
                              float* __restrict__ out, int* __restrict__ idxbuf,
                              float* __restrict__ counts,
                              int* __restrict__ offs, int* __restrict__ cursor,
                              float* __restrict__ cs_fin) {
    __shared__ int   hist[1024];
    __shared__ int   sc[1024];
    __shared__ float sb[1024];
    int k = threadIdx.x;
    hist[k] = 0;
    __syncthreads();
    const int nrc = rccnt[0];
    for (int i = k; i < nrc; i += 1024) {
        int grow = rclist[i];
        int bidx = (int)(packed[grow] & 0xFFFFFFFFull);
        out[IOFF + grow] = (float)bidx;
        idxbuf[grow] = bidx;                     // no DECIDED bit -> flagged
        atomicAdd(&hist[bidx], 1);
    }
    __syncthreads();
    int c = (int)counts[k] + hist[k];
    counts[k] = (float)c;                        // final counts for dw_q
    float ce = 0.99f * cluster_size[k] + 0.01f * (float)c;
    sc[k] = c;
    sb[k] = ce;
    __syncthreads();
    for (int off = 1; off < 1024; off <<= 1) {
        int v = (k >= off) ? sc[k - off] : 0;
        __syncthreads();
        sc[k] += v;
        __syncthreads();
    }
    offs[k] = sc[k] - c;
    cursor[k] = 0;
    for (int off = 512; off > 0; off >>= 1) {
        if (k < off) sb[k] += sb[k + off];
        __syncthreads();
    }
    float n = sb[0];
    float v = ((ce + 1e-5f) / (n + 0.01024f)) * n;
    out[CSOFF + k] = v;
    cs_fin[k] = v;
}

// ---- Kernel E: scatter rows into per-code buckets (flag -> bit 31) ----
__global__ void scatter_kernel(const int* __restrict__ idxbuf,
                               const int* __restrict__ offs,
                               int* __restrict__ cursor,
                               int* __restrict__ rowlist) {
    int r = blockIdx.x * blockDim.x + threadIdx.x;
    if (r >= NROWS) return;
    int v = idxbuf[r];
    int k = v & 1023;
    int pos = atomicAdd(&cursor[k], 1);
    rowlist[offs[k] + pos] = r | ((v & DECIDED_BIT) ? 0 : 0x80000000);
}

// ---- Kernel F: per-code dw reduction + fused EMA/new-weight; quantized
//      stores only for FLAGGED rows (bit 31 of rowlist entry). ----
__global__ __launch_bounds__(512) void dw_q_kernel(
    const float* __restrict__ x_in,
    const float* __restrict__ weight,
    const float* __restrict__ counts,
    const int* __restrict__ offs,
    const int* __restrict__ rowlist,
    const float* __restrict__ embed_avg,
    const float* __restrict__ cs_fin,
    float* __restrict__ out, float* __restrict__ dw) {
    __shared__ float wsh[64];
    __shared__ float part[8][64];

    const int k    = blockIdx.x;
    const int tid  = threadIdx.x;
    const int lane = tid & 63;
    const int wv   = tid >> 6;      // 0..7

    if (tid < 64) wsh[tid] = weight[(size_t)k * DD + tid];
    __syncthreads();

    const int cnt  = (int)counts[k];
    const int base = offs[k];
    const float wk = wsh[lane];

    float acc = 0.f;
    int i = wv;
    // 4 rows in flight per wave (stride 8 per wave, 8 waves).
    for (; i + 24 < cnt; i += 32) {
        int e0 = rowlist[base + i];
        int e1 = rowlist[base + i + 8];
        int e2 = rowlist[base + i + 16];
        int e3 = rowlist[base + i + 24];
        int r0 = e0 & 0x7fffffff;
        int r1 = e1 & 0x7fffffff;
        int r2 = e2 & 0x7fffffff;
        int r3 = e3 & 0x7fffffff;
        float x0 = x_in[(size_t)r0 * DD + lane];
        float x1 = x_in[(size_t)r1 * DD + lane];
        float x2 = x_in[(size_t)r2 * DD + lane];
        float x3 = x_in[(size_t)r3 * DD + lane];
        if (e0 < 0) out[QOFF + (size_t)r0 * DD + lane] = __fadd_rn(x0, __fsub_rn(wk, x0));
        if (e1 < 0) out[QOFF + (size_t)r1 * DD + lane] = __fadd_rn(x1, __fsub_rn(wk, x1));
        if (e2 < 0) out[QOFF + (size_t)r2 * DD + lane] = __fadd_rn(x2, __fsub_rn(wk, x2));
        if (e3 < 0) out[QOFF + (size_t)r3 * DD + lane] = __fadd_rn(x3, __fsub_rn(wk, x3));
        acc = __fadd_rn(acc, x0);
        acc = __fadd_rn(acc, x1);
        acc = __fadd_rn(acc, x2);
        acc = __fadd_rn(acc, x3);
    }
    for (; i < cnt; i += 8) {
        int e = rowlist[base + i];
        int r = e & 0x7fffffff;
        float xq = x_in[(size_t)r * DD + lane];
        if (e < 0) out[QOFF + (size_t)r * DD + lane] = __fadd_rn(xq, __fsub_rn(wk, xq));
        acc = __fadd_rn(acc, xq);
    }
    part[wv][lane] = acc;
    __syncthreads();
    if (tid < 64) {
        float s01 = __fadd_rn(part[0][tid], part[1][tid]);
        float s23 = __fadd_rn(part[2][tid], part[3][tid]);
        float s45 = __fadd_rn(part[4][tid], part[5][tid]);
        float s67 = __fadd_rn(part[6][tid], part[7][tid]);
        float s = __fadd_rn(__fadd_rn(s01, s23), __fadd_rn(s45, s67));
        int e = k * DD + tid;
        dw[e] = s;
        float na = 0.99f * embed_avg[e] + 0.01f * s;
        out[EAOFF + e] = na;
        out[WOFF + e] = na / cs_fin[k];
    }
}

extern "C" void kernel_launch(void* const* d_in, const int* in_sizes, int n_in,
                              void* d_out, int out_size, void* d_ws, size_t ws_size,
                              hipStream_t stream) {
    (void)in_sizes; (void)n_in; (void)out_size; (void)ws_size;
    const float* x       = (const float*)d_in[0];
    const float* weight  = (const float*)d_in[1];
    const float* cluster = (const float*)d_in[2];
    const float* eavg    = (const float*)d_in[3];
    float* out = (float*)d_out;
    float* wsf = (float*)d_ws;

    float*    code_sq = wsf + WS_CODESQ;
    float*    counts  = wsf + WS_COUNTS;
    int*      rccnt   = (int*)(wsf + WS_RCCNT);
    int*      cursor  = (int*)(wsf + WS_CURSOR);
    int*      offs    = (int*)(wsf + WS_OFFS);
    float*    cs_fin  = wsf + WS_CSFIN;
    float*    dwbuf   = wsf + WS_DW;
    _Float16* wswz    = (_Float16*)(wsf + WS_WSWZ);
    int*      idxbuf  = (int*)(wsf + WS_IDX);
    int*      rclist  = (int*)(wsf + WS_RCLIST);
    int*      rowlist = (int*)(wsf + WS_ROWLIST);
    unsigned long long* packed = (unsigned long long*)(wsf + WS_PACKED);

    hipLaunchKernelGGL(prep_kernel, dim3(16), dim3(64), 0, stream,
                       weight, code_sq, wswz, counts, rccnt);
    hipLaunchKernelGGL(vq_scan, dim3(1024), dim3(256), 0, stream,
                       x, weight, code_sq, wswz, out, counts, idxbuf, rccnt,
                       rclist, packed);
    hipLaunchKernelGGL(vq_recheck, dim3(2048), dim3(256), 0, stream,
                       x, weight, code_sq, packed, rccnt, rclist);
    hipLaunchKernelGGL(rc_offsets_cs, dim3(1), dim3(1024), 0, stream,
                       packed, rccnt, rclist, cluster, out, idxbuf, counts,
                       offs, cursor, cs_fin);
    hipLaunchKernelGGL(scatter_kernel, dim3(256), dim3(256), 0, stream,
                       idxbuf, offs, cursor, rowlist);
    hipLaunchKernelGGL(dw_q_kernel, dim3(1024), dim3(512), 0, stream,
                       x, weight, counts, offs, rowlist, eavg, cs_fin, out, dwbuf);
}